// Round 3
// baseline (497.780 us; speedup 1.0000x reference)
//
#include <hip/hip_runtime.h>
#include <stdint.h>

#define B_ 2
#define S_ 2048
#define C_ 768
#define H_ 8
#define DH 96
#define CTX 128
#define I_ 3072
#define M_ (B_*S_)
#define N3 (3*C_)

typedef unsigned short u16;
typedef __bf16 bf16x8 __attribute__((ext_vector_type(8)));
typedef float f32x4 __attribute__((ext_vector_type(4)));

__device__ __forceinline__ u16 f2b(float f){
  union { float f; uint32_t u; } v; v.f = f;
  uint32_t r = (v.u + 0x7FFFu + ((v.u >> 16) & 1u)) >> 16;
  return (u16)r;
}
__device__ __forceinline__ float b2f(u16 h){
  union { uint32_t u; float f; } v; v.u = ((uint32_t)h) << 16;
  return v.f;
}
__device__ __forceinline__ void gload_lds16(const void* g, void* l){
  __builtin_amdgcn_global_load_lds((const __attribute__((address_space(1))) void*)g,
                                   (__attribute__((address_space(3))) void*)l, 16, 0, 0);
}

// ---------------- fused weight convert+transpose: W (K,N) f32 -> Wt (N,K) bf16, 9 mats in 1 launch ----------------
struct WEnt { const float* src; u16* dst; int K; int N; int t0; };
struct WPack { WEnt e[9]; };

__global__ __launch_bounds__(256) void wconv_all_kernel(WPack p){
  __shared__ float tile[32][33];
  const int t = blockIdx.x;
  int i = 0;
  #pragma unroll
  for(int j=1;j<9;j++) if(t >= p.e[j].t0) i = j;
  const float* __restrict__ Wsrc = p.e[i].src;
  u16* __restrict__ Wt = p.e[i].dst;
  const int K = p.e[i].K, N = p.e[i].N;
  const int rel = t - p.e[i].t0;
  const int ntx = N >> 5;
  const int n0 = (rel % ntx) << 5, k0 = (rel / ntx) << 5;
  const int tx = threadIdx.x & 31, ty = threadIdx.x >> 5;
  #pragma unroll
  for(int q=0;q<4;q++)
    tile[ty + q*8][tx] = Wsrc[(size_t)(k0 + ty + q*8) * N + n0 + tx];
  __syncthreads();
  #pragma unroll
  for(int q=0;q<4;q++)
    Wt[(size_t)(n0 + ty + q*8) * K + k0 + tx] = f2b(tile[tx][ty + q*8]);
}

// ---------------- f32 -> bf16 ----------------
__global__ void cvt_kernel(const float* __restrict__ in, u16* __restrict__ out, int n){
  int i = blockIdx.x*256 + threadIdx.x;
  if(i < n) out[i] = f2b(in[i]);
}

// ---------------- LayerNorm over rows of 768, bf16 out ----------------
__global__ __launch_bounds__(256) void ln_kernel(const float* __restrict__ x, const float* __restrict__ g,
    const float* __restrict__ bb, u16* __restrict__ out)
{
  const int row = blockIdx.x;
  const int t = threadIdx.x;
  const float* xr = x + (size_t)row * C_;
  float v0 = xr[t], v1 = xr[t+256], v2 = xr[t+512];
  float s = v0+v1+v2;
  float s2 = v0*v0 + v1*v1 + v2*v2;
  #pragma unroll
  for(int off=32; off>0; off>>=1){ s += __shfl_down(s, off); s2 += __shfl_down(s2, off); }
  __shared__ float red[8];
  const int lane = t & 63, wv = t >> 6;
  if(lane == 0){ red[wv] = s; red[4+wv] = s2; }
  __syncthreads();
  s = red[0]+red[1]+red[2]+red[3];
  s2 = red[4]+red[5]+red[6]+red[7];
  const float mu = s * (1.0f/C_);
  const float inv = rsqrtf(s2*(1.0f/C_) - mu*mu + 1e-5f);
  u16* orow = out + (size_t)row*C_;
  orow[t]     = f2b((v0-mu)*inv*g[t]     + bb[t]);
  orow[t+256] = f2b((v1-mu)*inv*g[t+256] + bb[t+256]);
  orow[t+512] = f2b((v2-mu)*inv*g[t+512] + bb[t+512]);
}

// ---------------- GEMM: A (M,K) bf16 @ Bt (N,K) bf16 -> bf16 out or f32(acc+resid) ----------------
__global__ __launch_bounds__(256) void gemm_kernel(
    const u16* __restrict__ A, const u16* __restrict__ Bt,
    u16* __restrict__ Ob, float* __restrict__ Of, const float* __restrict__ resid,
    int Mdim, int Ndim, int Kdim, int outF32)
{
  __shared__ __align__(16) u16 As[128*32];
  __shared__ __align__(16) u16 Bs[128*32];
  const int tid = threadIdx.x;
  const int lane = tid & 63, w = tid >> 6;
  const int wm = w >> 1, wn = w & 1;
  const int m0 = blockIdx.y * 128, n0 = blockIdx.x * 128;
  f32x4 acc[4][4] = {};
  const int sr = tid >> 2;
  const int sc = (tid & 3) << 3;
  const int l15 = lane & 15, lk = (lane >> 4) << 3;
  for(int k0 = 0; k0 < Kdim; k0 += 32){
    #pragma unroll
    for(int j = 0; j < 2; j++){
      gload_lds16(A  + (size_t)(m0 + sr + (j<<6)) * Kdim + k0 + sc, As + (tid<<3) + (j<<11));
      gload_lds16(Bt + (size_t)(n0 + sr + (j<<6)) * Kdim + k0 + sc, Bs + (tid<<3) + (j<<11));
    }
    __syncthreads();
    bf16x8 af[4], bfr[4];
    #pragma unroll
    for(int i=0;i<4;i++) af[i]  = *(const bf16x8*)(As + (wm*64 + i*16 + l15)*32 + lk);
    #pragma unroll
    for(int i=0;i<4;i++) bfr[i] = *(const bf16x8*)(Bs + (wn*64 + i*16 + l15)*32 + lk);
    #pragma unroll
    for(int mi=0;mi<4;mi++)
      #pragma unroll
      for(int ni=0;ni<4;ni++)
        acc[mi][ni] = __builtin_amdgcn_mfma_f32_16x16x32_bf16(af[mi], bfr[ni], acc[mi][ni], 0,0,0);
    __syncthreads();
  }
  const int rbase = m0 + wm*64 + ((lane>>4)<<2);
  const int cbase = n0 + wn*64 + l15;
  if(outF32){
    #pragma unroll
    for(int mi=0;mi<4;mi++)
      #pragma unroll
      for(int ni=0;ni<4;ni++)
        #pragma unroll
        for(int r=0;r<4;r++){
          size_t idx = (size_t)(rbase + mi*16 + r) * Ndim + cbase + ni*16;
          Of[idx] = acc[mi][ni][r] + resid[idx];
        }
  } else {
    #pragma unroll
    for(int mi=0;mi<4;mi++)
      #pragma unroll
      for(int ni=0;ni<4;ni++)
        #pragma unroll
        for(int r=0;r<4;r++){
          size_t idx = (size_t)(rbase + mi*16 + r) * Ndim + cbase + ni*16;
          Ob[idx] = f2b(acc[mi][ni][r]);
        }
  }
}

// ---------------- RoPE in-place on q,k slices of qkv (bf16), 16B vectorized ----------------
__global__ void rope_kernel(u16* qkv, const int* hp, const int* wp){
  const int W = wp[0], HH = hp[0];
  int idx = blockIdx.x*256 + threadIdx.x;
  if(idx >= M_*H_*6) return;
  const int c = idx % 6;          // chunk of 8 dims within [0,48)
  int t1 = idx / 6;
  const int h = t1 & 7;
  const int m = t1 >> 3;
  const int d0 = c*8;
  const int s = m & (S_-1);
  const int xc = s % W;
  const int y  = (s / W) % HH;
  const int tf = s / (W*HH);
  float c1v[8], s1v[8], c2v[8], s2v[8];
  #pragma unroll
  for(int j=0;j<8;j++){
    const int d = d0 + j;
    const float invf = __powf(10000.0f, -(float)(d & 15) * (1.0f/16.0f));
    const float pos1 = (float)(d < 32 ? xc : y);
    const float pos2 = (float)(d < 16 ? y : tf);
    __sincosf(pos1 * invf, &s1v[j], &c1v[j]);
    __sincosf(pos2 * invf, &s2v[j], &c2v[j]);
  }
  const size_t base = (size_t)m * N3 + h*DH + d0;
  #pragma unroll
  for(int part=0; part<2; part++){
    u16* p = qkv + base + (size_t)part*C_;
    uint4 lo = *(const uint4*)p;
    uint4 hi = *(const uint4*)(p + 48);
    const u16* lw = (const u16*)&lo; const u16* hw = (const u16*)&hi;
    uint4 olo, ohi; u16* ol = (u16*)&olo; u16* oh = (u16*)&ohi;
    #pragma unroll
    for(int j=0;j<8;j++){
      float x1 = b2f(lw[j]), x2 = b2f(hw[j]);
      ol[j] = f2b(x1*c1v[j] - x2*s1v[j]);
      oh[j] = f2b(x2*c2v[j] + x1*s2v[j]);
    }
    *(uint4*)p = olo;
    *(uint4*)(p + 48) = ohi;
  }
}

// ---------------- V transpose ----------------
__global__ __launch_bounds__(256) void vt_kernel(const u16* __restrict__ src, u16* __restrict__ dst,
                                                 int rowStride, int colOff, int seqLen){
  const int bh = blockIdx.y, b = bh >> 3, h = bh & 7;
  const int s0 = blockIdx.x*64;
  __shared__ u16 t[64][DH+8];
  const int tid = threadIdx.x;
  #pragma unroll
  for(int i=0;i<24;i++){
    int e = tid + i*256; int si = e/DH, d = e - si*DH;
    t[si][d] = src[(size_t)(b*seqLen + s0+si)*rowStride + colOff + h*DH + d];
  }
  __syncthreads();
  #pragma unroll
  for(int i=0;i<24;i++){
    int e = tid + i*256; int d = e >> 6, si = e & 63;
    dst[((size_t)bh*DH + d)*seqLen + s0 + si] = t[si][d];
  }
}

// ---------------- Flash attention: barrier-free, 2 waves x 32 q-rows, K/V direct from L2 ----------------
// Block = 128 threads (2 waves). Each wave owns 32 q-rows (2 M-frags), iterates kv tiles of 64.
// No __syncthreads in main loop: P buffer is per-wave private LDS. XCD remap: lin%8 selects head
// so each XCD's L2 holds only 2 heads' K/V (~1.5 MB).
__global__ __launch_bounds__(128, 2) void attn_kernel(
    const u16* __restrict__ qp, int qStride, int qOff,
    const u16* __restrict__ kp, int kStride, int kOff,
    const u16* __restrict__ vt,   // (bh, DH, kvLen)
    u16* __restrict__ op,         // (B*S, C) at col h*DH
    int kvLen, int causal)
{
  __shared__ __align__(16) u16 Plds[2][32][72];
  const int lin = blockIdx.x + blockIdx.y * 32;   // gridDim.x == 32 always
  const int xcd = lin & 7, g = lin >> 3;
  const int qt_raw = g & 31, hi = g >> 5;
  const int bh = xcd + (hi << 3);
  const int b = bh >> 3, h = bh & 7;
  const int qt = (causal && hi) ? (31 - qt_raw) : qt_raw;   // long+short pairing per XCD
  const int q0 = qt * 64;
  const int tid = threadIdx.x;
  const int lane = tid & 63, w = tid >> 6;
  const int l15 = lane & 15, lg = lane >> 4, lk = lg << 3;
  const int qrb = q0 + w*32;
  const float scale = 0.1020620726159658f;  // 96^-0.5

  bf16x8 qf[2][3];
  #pragma unroll
  for(int f=0;f<2;f++){
    const size_t qb = (size_t)(b*S_ + qrb + f*16 + l15) * qStride + qOff + h*DH;
    #pragma unroll
    for(int ks=0;ks<3;ks++) qf[f][ks] = *(const bf16x8*)(qp + qb + ks*32 + lk);
  }
  const u16* kbase = kp + (size_t)b*kvLen*kStride + kOff + h*DH;
  const u16* vbase = vt + (size_t)bh*DH*kvLen;

  f32x4 oacc[2][6] = {};
  float mrow[2][4], lrow[2][4];
  #pragma unroll
  for(int f=0;f<2;f++)
    #pragma unroll
    for(int r=0;r<4;r++){ mrow[f][r] = -3e38f; lrow[f][r] = 0.f; }

  const int nT = (causal ? (q0 + 64) : kvLen) >> 6;
  for(int t=0; t<nT; t++){
    const int kv0 = t << 6;
    // === QK^T: K frags straight from global (L2-resident), shared across both q-frags ===
    f32x4 sacc[2][4] = {};
    __builtin_amdgcn_s_setprio(1);
    #pragma unroll
    for(int nt=0;nt<4;nt++){
      const size_t kb = (size_t)(kv0 + nt*16 + l15) * kStride;
      bf16x8 kf[3];
      #pragma unroll
      for(int ks=0;ks<3;ks++) kf[ks] = *(const bf16x8*)(kbase + kb + ks*32 + lk);
      #pragma unroll
      for(int f=0;f<2;f++)
        #pragma unroll
        for(int ks=0;ks<3;ks++)
          sacc[f][nt] = __builtin_amdgcn_mfma_f32_16x16x32_bf16(qf[f][ks], kf[ks], sacc[f][nt], 0,0,0);
    }
    __builtin_amdgcn_s_setprio(0);
    // === mask + online softmax (two independent chains f=0,1) ===
    #pragma unroll
    for(int f=0;f<2;f++){
      const int rowb = qrb + f*16;
      const bool dm = (causal != 0) && (kv0 + 64 > rowb);
      float mt[4];
      #pragma unroll
      for(int r=0;r<4;r++) mt[r] = -3e38f;
      #pragma unroll
      for(int nt=0;nt<4;nt++)
        #pragma unroll
        for(int r=0;r<4;r++){
          float v = sacc[f][nt][r] * scale;
          if(dm && (kv0 + nt*16 + l15 > rowb + (lg<<2) + r)) v = -3e38f;
          sacc[f][nt][r] = v;
          mt[r] = fmaxf(mt[r], v);
        }
      #pragma unroll
      for(int r=0;r<4;r++){
        #pragma unroll
        for(int off=1; off<16; off<<=1) mt[r] = fmaxf(mt[r], __shfl_xor(mt[r], off));
      }
      float al[4], rs[4];
      #pragma unroll
      for(int r=0;r<4;r++){
        float mn = fmaxf(mrow[f][r], mt[r]);
        al[r] = __expf(mrow[f][r] - mn);
        mrow[f][r] = mn;
        rs[r] = 0.f;
      }
      #pragma unroll
      for(int nt=0;nt<4;nt++)
        #pragma unroll
        for(int r=0;r<4;r++){
          float pv = __expf(sacc[f][nt][r] - mrow[f][r]);
          sacc[f][nt][r] = pv;
          rs[r] += pv;
        }
      #pragma unroll
      for(int r=0;r<4;r++){
        #pragma unroll
        for(int off=1; off<16; off<<=1) rs[r] += __shfl_xor(rs[r], off);
        lrow[f][r] = lrow[f][r]*al[r] + rs[r];
      }
      #pragma unroll
      for(int n=0;n<6;n++)
        #pragma unroll
        for(int r=0;r<4;r++) oacc[f][n][r] *= al[r];
      // P -> per-wave LDS (padded stride 72: conflict-free)
      #pragma unroll
      for(int nt=0;nt<4;nt++)
        #pragma unroll
        for(int r=0;r<4;r++)
          Plds[w][f*16 + (lg<<2)+r][nt*16+l15] = f2b(sacc[f][nt][r]);
    }
    // === PV: V frags straight from global, P from private LDS ===
    #pragma unroll
    for(int kk=0;kk<2;kk++){
      bf16x8 vf[6];
      #pragma unroll
      for(int n=0;n<6;n++)
        vf[n] = *(const bf16x8*)(vbase + (size_t)(n*16+l15)*kvLen + kv0 + kk*32 + lk);
      bf16x8 pf[2];
      #pragma unroll
      for(int f=0;f<2;f++) pf[f] = *(const bf16x8*)(&Plds[w][f*16 + l15][kk*32 + lk]);
      __builtin_amdgcn_s_setprio(1);
      #pragma unroll
      for(int f=0;f<2;f++)
        #pragma unroll
        for(int n=0;n<6;n++)
          oacc[f][n] = __builtin_amdgcn_mfma_f32_16x16x32_bf16(pf[f], vf[n], oacc[f][n], 0,0,0);
      __builtin_amdgcn_s_setprio(0);
    }
  }
  #pragma unroll
  for(int f=0;f<2;f++)
    #pragma unroll
    for(int n=0;n<6;n++)
      #pragma unroll
      for(int r=0;r<4;r++){
        const int qq = qrb + f*16 + (lg<<2) + r;
        op[(size_t)(b*S_ + qq)*C_ + h*DH + n*16 + l15] = f2b(oacc[f][n][r] / lrow[f][r]);
      }
}

// ---------------- SiLU(gate) * up from fused (M, 2I) buffer -> (M, I) bf16, 8-wide ----------------
__global__ void silu_kernel(const u16* __restrict__ gu, u16* __restrict__ obuf, int n8){
  int i = blockIdx.x*256 + threadIdx.x;
  if(i >= n8) return;
  int m = i / (I_/8), c = i - m*(I_/8);
  const uint4 g = *(const uint4*)(gu + (size_t)m*(2*I_) + c*8);
  const uint4 u = *(const uint4*)(gu + (size_t)m*(2*I_) + I_ + c*8);
  const u16* gp = (const u16*)&g; const u16* up = (const u16*)&u;
  uint4 o;
  u16* opw = (u16*)&o;
  #pragma unroll
  for(int j=0;j<8;j++){
    float xg = b2f(gp[j]), yu = b2f(up[j]);
    opw[j] = f2b(xg / (1.0f + __expf(-xg)) * yu);
  }
  *(uint4*)(obuf + (size_t)i*8) = o;
}

extern "C" void kernel_launch(void* const* d_in, const int* in_sizes, int n_in,
                              void* d_out, int out_size, void* d_ws, size_t ws_size,
                              hipStream_t stream)
{
  (void)in_sizes; (void)n_in; (void)out_size;
  const float* x    = (const float*)d_in[0];
  const float* ctxF = (const float*)d_in[1];
  const float* wqkvF= (const float*)d_in[2];
  const float* waoF = (const float*)d_in[3];
  const float* ln1g = (const float*)d_in[4];
  const float* ln1b = (const float*)d_in[5];
  const float* wqcF = (const float*)d_in[6];
  const float* wkcF = (const float*)d_in[7];
  const float* wvcF = (const float*)d_in[8];
  const float* wcoF = (const float*)d_in[9];
  const float* ln2g = (const float*)d_in[10];
  const float* ln2b = (const float*)d_in[11];
  const float* wgF  = (const float*)d_in[12];
  const float* wuF  = (const float*)d_in[13];
  const float* wdF  = (const float*)d_in[14];
  const float* ln3g = (const float*)d_in[15];
  const float* ln3b = (const float*)d_in[16];
  const int* hgt = (const int*)d_in[17];
  const int* wid = (const int*)d_in[18];
  float* out = (float*)d_out;

  char* base = (char*)d_ws;
  size_t off = 0;
  auto alloc = [&](size_t bytes)->void*{
    void* r = base + off;
    off += (bytes + 255) & ~(size_t)255;
    return r;
  };
  u16* wqkvT = (u16*)alloc((size_t)N3*C_*2);
  u16* waoT  = (u16*)alloc((size_t)C_*C_*2);
  u16* wqcT  = (u16*)alloc((size_t)C_*C_*2);
  u16* wkvcT = (u16*)alloc((size_t)2*C_*C_*2);
  u16* wcoT  = (u16*)alloc((size_t)C_*C_*2);
  u16* wguT  = (u16*)alloc((size_t)2*I_*C_*2);
  u16* wdT   = (u16*)alloc((size_t)C_*I_*2);
  u16* ctxb  = (u16*)alloc((size_t)B_*CTX*C_*2);
  u16* xn    = (u16*)alloc((size_t)M_*C_*2);
  u16* gateb = (u16*)alloc((size_t)M_*I_*2);
  float* x1  = (float*)alloc((size_t)M_*C_*4);
  float* x2  = (float*)alloc((size_t)M_*C_*4);
  char* uni  = (char*)alloc((size_t)M_*2*I_*2);  // 50.33 MB transient union
  u16* qkvb = (u16*)uni;                                      // 18.87 MB
  u16* vtb  = (u16*)(uni + 18874368);                         //  6.29 MB
  u16* obuf = (u16*)(uni + 18874368 + 1*6291456);             //  6.29 MB
  u16* qcb  = (u16*)(uni + 18874368 + 2*6291456);             //  6.29 MB
  u16* kvcb = (u16*)(uni + 18874368 + 3*6291456);             //  0.79 MB
  u16* vctb = (u16*)(uni + 18874368 + 3*6291456 + 786432);    //  0.39 MB
  u16* gub  = (u16*)uni;                                      // MLP phase only
  if(off > ws_size) return;

  dim3 blk(256);
  // fused weight conversion: 9 matrices, 1 launch
  WPack wp;
  wp.e[0] = { wqkvF, wqkvT,               C_, N3,   0 };
  wp.e[1] = { waoF,  waoT,                C_, C_,   1728 };
  wp.e[2] = { wqcF,  wqcT,                C_, C_,   2304 };
  wp.e[3] = { wkcF,  wkvcT,               C_, C_,   2880 };
  wp.e[4] = { wvcF,  wkvcT + (size_t)C_*C_, C_, C_, 3456 };
  wp.e[5] = { wcoF,  wcoT,                C_, C_,   4032 };
  wp.e[6] = { wgF,   wguT,                C_, I_,   4608 };
  wp.e[7] = { wuF,   wguT + (size_t)I_*C_,  C_, I_, 6912 };
  wp.e[8] = { wdF,   wdT,                 I_, C_,   9216 };
  wconv_all_kernel<<<dim3(11520), blk, 0, stream>>>(wp);
  cvt_kernel<<<dim3((B_*CTX*C_+255)/256), blk, 0, stream>>>(ctxF, ctxb, B_*CTX*C_);

  // ---- self attention ----
  ln_kernel<<<dim3(M_), blk, 0, stream>>>(x, ln1g, ln1b, xn);
  gemm_kernel<<<dim3(N3/128, M_/128), blk, 0, stream>>>(xn, wqkvT, qkvb, nullptr, nullptr, M_, N3, C_, 0);
  rope_kernel<<<dim3((M_*H_*6+255)/256), blk, 0, stream>>>(qkvb, hgt, wid);
  vt_kernel<<<dim3(S_/64, B_*H_), blk, 0, stream>>>(qkvb, vtb, N3, 2*C_, S_);
  attn_kernel<<<dim3(S_/64, B_*H_), dim3(128), 0, stream>>>(qkvb, N3, 0, qkvb, N3, C_, vtb, obuf, S_, 1);
  gemm_kernel<<<dim3(C_/128, M_/128), blk, 0, stream>>>(obuf, waoT, nullptr, x1, x, M_, C_, C_, 1);

  // ---- cross attention ----
  ln_kernel<<<dim3(M_), blk, 0, stream>>>(x1, ln2g, ln2b, xn);
  gemm_kernel<<<dim3(C_/128, M_/128), blk, 0, stream>>>(xn, wqcT, qcb, nullptr, nullptr, M_, C_, C_, 0);
  gemm_kernel<<<dim3(2*C_/128, (B_*CTX)/128), blk, 0, stream>>>(ctxb, wkvcT, kvcb, nullptr, nullptr, B_*CTX, 2*C_, C_, 0);
  vt_kernel<<<dim3(CTX/64, B_*H_), blk, 0, stream>>>(kvcb, vctb, 2*C_, C_, CTX);
  attn_kernel<<<dim3(S_/64, B_*H_), dim3(128), 0, stream>>>(qcb, C_, 0, kvcb, 2*C_, 0, vctb, obuf, CTX, 0);
  gemm_kernel<<<dim3(C_/128, M_/128), blk, 0, stream>>>(obuf, wcoT, nullptr, x2, x1, M_, C_, C_, 1);

  // ---- MLP ----
  ln_kernel<<<dim3(M_), blk, 0, stream>>>(x2, ln3g, ln3b, xn);
  gemm_kernel<<<dim3(2*I_/128, M_/128), blk, 0, stream>>>(xn, wguT, gub, nullptr, nullptr, M_, 2*I_, C_, 0);
  silu_kernel<<<dim3(M_*I_/8/256), blk, 0, stream>>>(gub, gateb, M_*I_/8);
  gemm_kernel<<<dim3(C_/128, M_/128), blk, 0, stream>>>(gateb, wdT, nullptr, out, x2, M_, C_, I_, 1);
}

// Round 4
// 450.252 us; speedup vs baseline: 1.1056x; 1.1056x over previous
//
#include <hip/hip_runtime.h>
#include <stdint.h>

#define B_ 2
#define S_ 2048
#define C_ 768
#define H_ 8
#define DH 96
#define CTX 128
#define I_ 3072
#define M_ (B_*S_)
#define N3 (3*C_)

typedef unsigned short u16;
typedef __bf16 bf16x8 __attribute__((ext_vector_type(8)));
typedef float f32x4 __attribute__((ext_vector_type(4)));

__device__ __forceinline__ u16 f2b(float f){
  union { float f; uint32_t u; } v; v.f = f;
  uint32_t r = (v.u + 0x7FFFu + ((v.u >> 16) & 1u)) >> 16;
  return (u16)r;
}
__device__ __forceinline__ float b2f(u16 h){
  union { uint32_t u; float f; } v; v.u = ((uint32_t)h) << 16;
  return v.f;
}
__device__ __forceinline__ void gload_lds16(const void* g, void* l){
  __builtin_amdgcn_global_load_lds((const __attribute__((address_space(1))) void*)g,
                                   (__attribute__((address_space(3))) void*)l, 16, 0, 0);
}

// ---------------- fused weight convert+transpose: W (K,N) f32 -> Wt (N,K) bf16, 9 mats in 1 launch ----------------
struct WEnt { const float* src; u16* dst; int K; int N; int t0; };
struct WPack { WEnt e[9]; };

__global__ __launch_bounds__(256) void wconv_all_kernel(WPack p){
  __shared__ float tile[32][33];
  const int t = blockIdx.x;
  int i = 0;
  #pragma unroll
  for(int j=1;j<9;j++) if(t >= p.e[j].t0) i = j;
  const float* __restrict__ Wsrc = p.e[i].src;
  u16* __restrict__ Wt = p.e[i].dst;
  const int K = p.e[i].K, N = p.e[i].N;
  const int rel = t - p.e[i].t0;
  const int ntx = N >> 5;
  const int n0 = (rel % ntx) << 5, k0 = (rel / ntx) << 5;
  const int tx = threadIdx.x & 31, ty = threadIdx.x >> 5;
  #pragma unroll
  for(int q=0;q<4;q++)
    tile[ty + q*8][tx] = Wsrc[(size_t)(k0 + ty + q*8) * N + n0 + tx];
  __syncthreads();
  #pragma unroll
  for(int q=0;q<4;q++)
    Wt[(size_t)(n0 + ty + q*8) * K + k0 + tx] = f2b(tile[tx][ty + q*8]);
}

// ---------------- f32 -> bf16 ----------------
__global__ void cvt_kernel(const float* __restrict__ in, u16* __restrict__ out, int n){
  int i = blockIdx.x*256 + threadIdx.x;
  if(i < n) out[i] = f2b(in[i]);
}

// ---------------- LayerNorm over rows of 768, bf16 out ----------------
__global__ __launch_bounds__(256) void ln_kernel(const float* __restrict__ x, const float* __restrict__ g,
    const float* __restrict__ bb, u16* __restrict__ out)
{
  const int row = blockIdx.x;
  const int t = threadIdx.x;
  const float* xr = x + (size_t)row * C_;
  float v0 = xr[t], v1 = xr[t+256], v2 = xr[t+512];
  float s = v0+v1+v2;
  float s2 = v0*v0 + v1*v1 + v2*v2;
  #pragma unroll
  for(int off=32; off>0; off>>=1){ s += __shfl_down(s, off); s2 += __shfl_down(s2, off); }
  __shared__ float red[8];
  const int lane = t & 63, wv = t >> 6;
  if(lane == 0){ red[wv] = s; red[4+wv] = s2; }
  __syncthreads();
  s = red[0]+red[1]+red[2]+red[3];
  s2 = red[4]+red[5]+red[6]+red[7];
  const float mu = s * (1.0f/C_);
  const float inv = rsqrtf(s2*(1.0f/C_) - mu*mu + 1e-5f);
  u16* orow = out + (size_t)row*C_;
  orow[t]     = f2b((v0-mu)*inv*g[t]     + bb[t]);
  orow[t+256] = f2b((v1-mu)*inv*g[t+256] + bb[t+256]);
  orow[t+512] = f2b((v2-mu)*inv*g[t+512] + bb[t+512]);
}

// ---------------- GEMM: A (M,K) bf16 @ Bt (N,K) bf16 -> bf16 out or f32(acc+resid) ----------------
__global__ __launch_bounds__(256) void gemm_kernel(
    const u16* __restrict__ A, const u16* __restrict__ Bt,
    u16* __restrict__ Ob, float* __restrict__ Of, const float* __restrict__ resid,
    int Mdim, int Ndim, int Kdim, int outF32)
{
  __shared__ __align__(16) u16 As[128*32];
  __shared__ __align__(16) u16 Bs[128*32];
  const int tid = threadIdx.x;
  const int lane = tid & 63, w = tid >> 6;
  const int wm = w >> 1, wn = w & 1;
  const int m0 = blockIdx.y * 128, n0 = blockIdx.x * 128;
  f32x4 acc[4][4] = {};
  const int sr = tid >> 2;
  const int sc = (tid & 3) << 3;
  const int l15 = lane & 15, lk = (lane >> 4) << 3;
  for(int k0 = 0; k0 < Kdim; k0 += 32){
    #pragma unroll
    for(int j = 0; j < 2; j++){
      gload_lds16(A  + (size_t)(m0 + sr + (j<<6)) * Kdim + k0 + sc, As + (tid<<3) + (j<<11));
      gload_lds16(Bt + (size_t)(n0 + sr + (j<<6)) * Kdim + k0 + sc, Bs + (tid<<3) + (j<<11));
    }
    __syncthreads();
    bf16x8 af[4], bfr[4];
    #pragma unroll
    for(int i=0;i<4;i++) af[i]  = *(const bf16x8*)(As + (wm*64 + i*16 + l15)*32 + lk);
    #pragma unroll
    for(int i=0;i<4;i++) bfr[i] = *(const bf16x8*)(Bs + (wn*64 + i*16 + l15)*32 + lk);
    #pragma unroll
    for(int mi=0;mi<4;mi++)
      #pragma unroll
      for(int ni=0;ni<4;ni++)
        acc[mi][ni] = __builtin_amdgcn_mfma_f32_16x16x32_bf16(af[mi], bfr[ni], acc[mi][ni], 0,0,0);
    __syncthreads();
  }
  const int rbase = m0 + wm*64 + ((lane>>4)<<2);
  const int cbase = n0 + wn*64 + l15;
  if(outF32){
    #pragma unroll
    for(int mi=0;mi<4;mi++)
      #pragma unroll
      for(int ni=0;ni<4;ni++)
        #pragma unroll
        for(int r=0;r<4;r++){
          size_t idx = (size_t)(rbase + mi*16 + r) * Ndim + cbase + ni*16;
          Of[idx] = acc[mi][ni][r] + resid[idx];
        }
  } else {
    #pragma unroll
    for(int mi=0;mi<4;mi++)
      #pragma unroll
      for(int ni=0;ni<4;ni++)
        #pragma unroll
        for(int r=0;r<4;r++){
          size_t idx = (size_t)(rbase + mi*16 + r) * Ndim + cbase + ni*16;
          Ob[idx] = f2b(acc[mi][ni][r]);
        }
  }
}

// ---------------- RoPE in-place on q,k slices of qkv (bf16), 16B vectorized ----------------
__global__ void rope_kernel(u16* qkv, const int* hp, const int* wp){
  const int W = wp[0], HH = hp[0];
  int idx = blockIdx.x*256 + threadIdx.x;
  if(idx >= M_*H_*6) return;
  const int c = idx % 6;          // chunk of 8 dims within [0,48)
  int t1 = idx / 6;
  const int h = t1 & 7;
  const int m = t1 >> 3;
  const int d0 = c*8;
  const int s = m & (S_-1);
  const int xc = s % W;
  const int y  = (s / W) % HH;
  const int tf = s / (W*HH);
  float c1v[8], s1v[8], c2v[8], s2v[8];
  #pragma unroll
  for(int j=0;j<8;j++){
    const int d = d0 + j;
    const float invf = __powf(10000.0f, -(float)(d & 15) * (1.0f/16.0f));
    const float pos1 = (float)(d < 32 ? xc : y);
    const float pos2 = (float)(d < 16 ? y : tf);
    __sincosf(pos1 * invf, &s1v[j], &c1v[j]);
    __sincosf(pos2 * invf, &s2v[j], &c2v[j]);
  }
  const size_t base = (size_t)m * N3 + h*DH + d0;
  #pragma unroll
  for(int part=0; part<2; part++){
    u16* p = qkv + base + (size_t)part*C_;
    uint4 lo = *(const uint4*)p;
    uint4 hi = *(const uint4*)(p + 48);
    const u16* lw = (const u16*)&lo; const u16* hw = (const u16*)&hi;
    uint4 olo, ohi; u16* ol = (u16*)&olo; u16* oh = (u16*)&ohi;
    #pragma unroll
    for(int j=0;j<8;j++){
      float x1 = b2f(lw[j]), x2 = b2f(hw[j]);
      ol[j] = f2b(x1*c1v[j] - x2*s1v[j]);
      oh[j] = f2b(x2*c2v[j] + x1*s2v[j]);
    }
    *(uint4*)p = olo;
    *(uint4*)(p + 48) = ohi;
  }
}

// ---------------- V transpose ----------------
__global__ __launch_bounds__(256) void vt_kernel(const u16* __restrict__ src, u16* __restrict__ dst,
                                                 int rowStride, int colOff, int seqLen){
  const int bh = blockIdx.y, b = bh >> 3, h = bh & 7;
  const int s0 = blockIdx.x*64;
  __shared__ u16 t[64][DH+8];
  const int tid = threadIdx.x;
  #pragma unroll
  for(int i=0;i<24;i++){
    int e = tid + i*256; int si = e/DH, d = e - si*DH;
    t[si][d] = src[(size_t)(b*seqLen + s0+si)*rowStride + colOff + h*DH + d];
  }
  __syncthreads();
  #pragma unroll
  for(int i=0;i<24;i++){
    int e = tid + i*256; int d = e >> 6, si = e & 63;
    dst[((size_t)bh*DH + d)*seqLen + s0 + si] = t[si][d];
  }
}

// ---------------- Flash attention, split-KV. mode 0 = cross (no mask, whole kv, direct write),
// mode 1 = self causal, kv chunks of 1024: qt<16 -> 1 chunk direct; qt>=16 -> 2 chunks -> partials.
// Block: 256 thr / 4 waves, 64 q-rows, LDS-staged K/V (padded), reg prefetch, XCD head-grouping.
__global__ __launch_bounds__(256,4) void attn_kernel(
    const u16* __restrict__ qp, int qStride, int qOff,
    const u16* __restrict__ kp, int kStride, int kOff,
    const u16* __restrict__ vt,   // (bh, DH, kvLen)
    u16* __restrict__ op,         // (B*S, C) at col h*DH
    float* __restrict__ part,     // partials: [(bh*16+qt-16)*2+ch] * 6272 floats
    int kvLen, int mode)
{
  __shared__ __align__(16) u16 Ks[64][104];
  __shared__ __align__(16) u16 Vs[DH][72];
  __shared__ __align__(16) u16 Plds[4][16][72];
  const int lin = blockIdx.x;
  const int xcd = lin & 7;
  const int idx = lin >> 3;
  const int bh = xcd + ((idx & 1) << 3);   // 2 heads per XCD -> K/V L2-resident
  int qt, ch, nCh;
  if(mode == 0){ qt = idx >> 1; ch = 0; nCh = 1; }
  else {
    const int rest = idx >> 1;             // 0..47
    if(rest < 16){ qt = rest; ch = 0; nCh = 1; }
    else { qt = 16 + ((rest - 16) >> 1); ch = (rest - 16) & 1; nCh = 2; }
  }
  const int b = bh >> 3, h = bh & 7;
  const int q0 = qt << 6;
  const int kvA = ch << 10;
  const int kvB = mode ? min(kvA + 1024, q0 + 64) : kvLen;
  const int tA = kvA >> 6, tB = kvB >> 6;
  const int tid = threadIdx.x;
  const int lane = tid & 63, w = tid >> 6;
  const int l15 = lane & 15, lg = lane >> 4, lk = lg << 3;
  const int qrow_base = q0 + w*16;
  const float scale = 0.1020620726159658f;  // 96^-0.5

  bf16x8 qf[3];
  {
    const size_t qb = (size_t)(b*S_ + qrow_base + l15) * qStride + qOff + h*DH;
    #pragma unroll
    for(int ks=0;ks<3;ks++) qf[ks] = *(const bf16x8*)(qp + qb + ks*32 + lk);
  }

  int krow[3], kcol[3], vrow[3], vcol[3];
  #pragma unroll
  for(int r=0;r<3;r++){
    int c = r*256 + tid;
    krow[r] = c/12; kcol[r] = (c - krow[r]*12)*8;
    vrow[r] = c>>3; vcol[r] = (c&7)*8;
  }
  const u16* kbase = kp + (size_t)b*kvLen*kStride + kOff + h*DH;
  const u16* vbase = vt + (size_t)bh*DH*kvLen;

  uint4 kreg[3], vreg[3];
  #pragma unroll
  for(int r=0;r<3;r++){
    kreg[r] = *(const uint4*)(kbase + (size_t)(kvA + krow[r])*kStride + kcol[r]);
    vreg[r] = *(const uint4*)(vbase + (size_t)vrow[r]*kvLen + kvA + vcol[r]);
  }
  #pragma unroll
  for(int r=0;r<3;r++){
    *(uint4*)(&Ks[krow[r]][kcol[r]]) = kreg[r];
    *(uint4*)(&Vs[vrow[r]][vcol[r]]) = vreg[r];
  }
  __syncthreads();

  f32x4 oacc[6] = {};
  float mrow[4], lrow[4];
  #pragma unroll
  for(int r=0;r<4;r++){ mrow[r] = -3e38f; lrow[r] = 0.f; }

  for(int t=tA; t<tB; t++){
    const int kv0 = t << 6;
    if(t+1 < tB){
      #pragma unroll
      for(int r=0;r<3;r++){
        kreg[r] = *(const uint4*)(kbase + (size_t)(kv0+64+krow[r])*kStride + kcol[r]);
        vreg[r] = *(const uint4*)(vbase + (size_t)vrow[r]*kvLen + kv0+64 + vcol[r]);
      }
    }
    // === QK^T from LDS ===
    f32x4 sacc[4] = {};
    #pragma unroll
    for(int nt=0;nt<4;nt++){
      #pragma unroll
      for(int ks=0;ks<3;ks++){
        bf16x8 kf = *(const bf16x8*)(&Ks[nt*16+l15][ks*32+lk]);
        sacc[nt] = __builtin_amdgcn_mfma_f32_16x16x32_bf16(qf[ks], kf, sacc[nt], 0,0,0);
      }
    }
    // === mask + online softmax ===
    const bool doMask = (mode != 0) && (kv0 + 64 > qrow_base);
    float mt[4];
    #pragma unroll
    for(int r=0;r<4;r++) mt[r] = -3e38f;
    #pragma unroll
    for(int nt=0;nt<4;nt++)
      #pragma unroll
      for(int r=0;r<4;r++){
        float v = sacc[nt][r] * scale;
        if(doMask && (kv0 + nt*16 + l15 > qrow_base + (lg<<2) + r)) v = -3e38f;
        sacc[nt][r] = v;
        mt[r] = fmaxf(mt[r], v);
      }
    #pragma unroll
    for(int r=0;r<4;r++){
      #pragma unroll
      for(int off=1; off<16; off<<=1) mt[r] = fmaxf(mt[r], __shfl_xor(mt[r], off));
    }
    float al[4], rs[4];
    #pragma unroll
    for(int r=0;r<4;r++){
      float mn = fmaxf(mrow[r], mt[r]);
      al[r] = __expf(mrow[r] - mn);
      mrow[r] = mn;
      rs[r] = 0.f;
    }
    #pragma unroll
    for(int nt=0;nt<4;nt++)
      #pragma unroll
      for(int r=0;r<4;r++){
        float pv = __expf(sacc[nt][r] - mrow[r]);
        sacc[nt][r] = pv;
        rs[r] += pv;
      }
    #pragma unroll
    for(int r=0;r<4;r++){
      #pragma unroll
      for(int off=1; off<16; off<<=1) rs[r] += __shfl_xor(rs[r], off);
      lrow[r] = lrow[r]*al[r] + rs[r];
    }
    #pragma unroll
    for(int n=0;n<6;n++)
      #pragma unroll
      for(int r=0;r<4;r++) oacc[n][r] *= al[r];
    #pragma unroll
    for(int nt=0;nt<4;nt++)
      #pragma unroll
      for(int r=0;r<4;r++)
        Plds[w][(lg<<2)+r][nt*16+l15] = f2b(sacc[nt][r]);
    #pragma unroll
    for(int kk=0;kk<2;kk++){
      bf16x8 pf = *(const bf16x8*)(&Plds[w][l15][kk*32 + lk]);
      #pragma unroll
      for(int n=0;n<6;n++){
        bf16x8 vf = *(const bf16x8*)(&Vs[n*16+l15][kk*32+lk]);
        oacc[n] = __builtin_amdgcn_mfma_f32_16x16x32_bf16(pf, vf, oacc[n], 0,0,0);
      }
    }
    __syncthreads();
    if(t+1 < tB){
      #pragma unroll
      for(int r=0;r<3;r++){
        *(uint4*)(&Ks[krow[r]][kcol[r]]) = kreg[r];
        *(uint4*)(&Vs[vrow[r]][vcol[r]]) = vreg[r];
      }
      __syncthreads();
    }
  }
  if(nCh == 1){
    #pragma unroll
    for(int n=0;n<6;n++)
      #pragma unroll
      for(int r=0;r<4;r++){
        const int qq = qrow_base + (lg<<2) + r;
        op[(size_t)(b*S_ + qq)*C_ + h*DH + n*16 + l15] = f2b(oacc[n][r] / lrow[r]);
      }
  } else {
    float* pb = part + (size_t)((((bh<<4) + (qt-16))<<1) + ch) * 6272;
    #pragma unroll
    for(int n=0;n<6;n++)
      #pragma unroll
      for(int r=0;r<4;r++)
        pb[(w*16 + (lg<<2) + r)*96 + n*16 + l15] = oacc[n][r];
    if(l15 == 0){
      #pragma unroll
      for(int r=0;r<4;r++){
        pb[6144 + w*16 + (lg<<2) + r] = mrow[r];
        pb[6208 + w*16 + (lg<<2) + r] = lrow[r];
      }
    }
  }
}

// ---------------- combine 2 kv-chunk partials -> normalized bf16 output (qt>=16 only) ----------------
__global__ void attn_combine_kernel(const float* __restrict__ part, u16* __restrict__ op){
  const int i = blockIdx.x*256 + threadIdx.x;
  if(i >= 16*16*64*96) return;
  const int col = i % 96;
  const int r2 = i / 96;
  const int row = r2 & 63;
  const int r3 = r2 >> 6;
  const int qt16 = r3 & 15, bh = r3 >> 4;
  const float* p0 = part + (size_t)(((bh<<4)+qt16)<<1) * 6272;
  const float* p1 = p0 + 6272;
  const float m0 = p0[6144+row], l0 = p0[6208+row];
  const float m1 = p1[6144+row], l1 = p1[6208+row];
  const float Mx = fmaxf(m0, m1);
  const float w0 = __expf(m0-Mx), w1 = __expf(m1-Mx);
  const float o = (p0[row*96+col]*w0 + p1[row*96+col]*w1) / (l0*w0 + l1*w1);
  const int bq = bh >> 3, hq = bh & 7;
  const int q = ((qt16+16)<<6) + row;
  op[(size_t)(bq*S_ + q)*C_ + hq*DH + col] = f2b(o);
}

// ---------------- SiLU(gate) * up from fused (M, 2I) buffer -> (M, I) bf16, 8-wide ----------------
__global__ void silu_kernel(const u16* __restrict__ gu, u16* __restrict__ obuf, int n8){
  int i = blockIdx.x*256 + threadIdx.x;
  if(i >= n8) return;
  int m = i / (I_/8), c = i - m*(I_/8);
  const uint4 g = *(const uint4*)(gu + (size_t)m*(2*I_) + c*8);
  const uint4 u = *(const uint4*)(gu + (size_t)m*(2*I_) + I_ + c*8);
  const u16* gp = (const u16*)&g; const u16* up = (const u16*)&u;
  uint4 o;
  u16* opw = (u16*)&o;
  #pragma unroll
  for(int j=0;j<8;j++){
    float xg = b2f(gp[j]), yu = b2f(up[j]);
    opw[j] = f2b(xg / (1.0f + __expf(-xg)) * yu);
  }
  *(uint4*)(obuf + (size_t)i*8) = o;
}

extern "C" void kernel_launch(void* const* d_in, const int* in_sizes, int n_in,
                              void* d_out, int out_size, void* d_ws, size_t ws_size,
                              hipStream_t stream)
{
  (void)in_sizes; (void)n_in; (void)out_size;
  const float* x    = (const float*)d_in[0];
  const float* ctxF = (const float*)d_in[1];
  const float* wqkvF= (const float*)d_in[2];
  const float* waoF = (const float*)d_in[3];
  const float* ln1g = (const float*)d_in[4];
  const float* ln1b = (const float*)d_in[5];
  const float* wqcF = (const float*)d_in[6];
  const float* wkcF = (const float*)d_in[7];
  const float* wvcF = (const float*)d_in[8];
  const float* wcoF = (const float*)d_in[9];
  const float* ln2g = (const float*)d_in[10];
  const float* ln2b = (const float*)d_in[11];
  const float* wgF  = (const float*)d_in[12];
  const float* wuF  = (const float*)d_in[13];
  const float* wdF  = (const float*)d_in[14];
  const float* ln3g = (const float*)d_in[15];
  const float* ln3b = (const float*)d_in[16];
  const int* hgt = (const int*)d_in[17];
  const int* wid = (const int*)d_in[18];
  float* out = (float*)d_out;

  char* base = (char*)d_ws;
  size_t off = 0;
  auto alloc = [&](size_t bytes)->void*{
    void* r = base + off;
    off += (bytes + 255) & ~(size_t)255;
    return r;
  };
  u16* wqkvT = (u16*)alloc((size_t)N3*C_*2);
  u16* waoT  = (u16*)alloc((size_t)C_*C_*2);
  u16* wqcT  = (u16*)alloc((size_t)C_*C_*2);
  u16* wkvcT = (u16*)alloc((size_t)2*C_*C_*2);
  u16* wcoT  = (u16*)alloc((size_t)C_*C_*2);
  u16* wguT  = (u16*)alloc((size_t)2*I_*C_*2);
  u16* wdT   = (u16*)alloc((size_t)C_*I_*2);
  u16* ctxb  = (u16*)alloc((size_t)B_*CTX*C_*2);
  u16* xn    = (u16*)alloc((size_t)M_*C_*2);
  u16* gateb = (u16*)alloc((size_t)M_*I_*2);    // also holds attn partials (12.85 MB) pre-MLP
  float* x1  = (float*)alloc((size_t)M_*C_*4);
  float* x2  = (float*)alloc((size_t)M_*C_*4);
  char* uni  = (char*)alloc((size_t)M_*2*I_*2);  // 50.33 MB transient union
  u16* qkvb = (u16*)uni;                                      // 18.87 MB
  u16* vtb  = (u16*)(uni + 18874368);                         //  6.29 MB
  u16* obuf = (u16*)(uni + 18874368 + 1*6291456);             //  6.29 MB
  u16* qcb  = (u16*)(uni + 18874368 + 2*6291456);             //  6.29 MB
  u16* kvcb = (u16*)(uni + 18874368 + 3*6291456);             //  0.79 MB
  u16* vctb = (u16*)(uni + 18874368 + 3*6291456 + 786432);    //  0.39 MB
  u16* gub  = (u16*)uni;                                      // MLP phase only
  float* part = (float*)gateb;                                // attn phase only
  if(off > ws_size) return;

  dim3 blk(256);
  // fused weight conversion: 9 matrices, 1 launch
  WPack wp;
  wp.e[0] = { wqkvF, wqkvT,               C_, N3,   0 };
  wp.e[1] = { waoF,  waoT,                C_, C_,   1728 };
  wp.e[2] = { wqcF,  wqcT,                C_, C_,   2304 };
  wp.e[3] = { wkcF,  wkvcT,               C_, C_,   2880 };
  wp.e[4] = { wvcF,  wkvcT + (size_t)C_*C_, C_, C_, 3456 };
  wp.e[5] = { wcoF,  wcoT,                C_, C_,   4032 };
  wp.e[6] = { wgF,   wguT,                C_, I_,   4608 };
  wp.e[7] = { wuF,   wguT + (size_t)I_*C_,  C_, I_, 6912 };
  wp.e[8] = { wdF,   wdT,                 I_, C_,   9216 };
  wconv_all_kernel<<<dim3(11520), blk, 0, stream>>>(wp);
  cvt_kernel<<<dim3((B_*CTX*C_+255)/256), blk, 0, stream>>>(ctxF, ctxb, B_*CTX*C_);

  // ---- self attention ----
  ln_kernel<<<dim3(M_), blk, 0, stream>>>(x, ln1g, ln1b, xn);
  gemm_kernel<<<dim3(N3/128, M_/128), blk, 0, stream>>>(xn, wqkvT, qkvb, nullptr, nullptr, M_, N3, C_, 0);
  rope_kernel<<<dim3((M_*H_*6+255)/256), blk, 0, stream>>>(qkvb, hgt, wid);
  vt_kernel<<<dim3(S_/64, B_*H_), blk, 0, stream>>>(qkvb, vtb, N3, 2*C_, S_);
  attn_kernel<<<dim3(768), blk, 0, stream>>>(qkvb, N3, 0, qkvb, N3, C_, vtb, obuf, part, S_, 1);
  attn_combine_kernel<<<dim3(16*16*64*96/256), blk, 0, stream>>>(part, obuf);
  gemm_kernel<<<dim3(C_/128, M_/128), blk, 0, stream>>>(obuf, waoT, nullptr, x1, x, M_, C_, C_, 1);

  // ---- cross attention ----
  ln_kernel<<<dim3(M_), blk, 0, stream>>>(x1, ln2g, ln2b, xn);
  gemm_kernel<<<dim3(C_/128, M_/128), blk, 0, stream>>>(xn, wqcT, qcb, nullptr, nullptr, M_, C_, C_, 0);
  gemm_kernel<<<dim3(2*C_/128, (B_*CTX)/128), blk, 0, stream>>>(ctxb, wkvcT, kvcb, nullptr, nullptr, B_*CTX, 2*C_, C_, 0);
  vt_kernel<<<dim3(CTX/64, B_*H_), blk, 0, stream>>>(kvcb, vctb, 2*C_, C_, CTX);
  attn_kernel<<<dim3(512), blk, 0, stream>>>(qcb, C_, 0, kvcb, 2*C_, 0, vctb, obuf, nullptr, CTX, 0);
  gemm_kernel<<<dim3(C_/128, M_/128), blk, 0, stream>>>(obuf, wcoT, nullptr, x2, x1, M_, C_, C_, 1);

  // ---- MLP ----
  ln_kernel<<<dim3(M_), blk, 0, stream>>>(x2, ln3g, ln3b, xn);
  gemm_kernel<<<dim3(2*I_/128, M_/128), blk, 0, stream>>>(xn, wguT, gub, nullptr, nullptr, M_, 2*I_, C_, 0);
  silu_kernel<<<dim3(M_*I_/8/256), blk, 0, stream>>>(gub, gateb, M_*I_/8);
  gemm_kernel<<<dim3(C_/128, M_/128), blk, 0, stream>>>(gateb, wdT, nullptr, out, x2, M_, C_, I_, 1);
}

// Round 5
// 440.075 us; speedup vs baseline: 1.1311x; 1.0231x over previous
//
#include <hip/hip_runtime.h>
#include <stdint.h>

#define B_ 2
#define S_ 2048
#define C_ 768
#define H_ 8
#define DH 96
#define CTX 128
#define I_ 3072
#define M_ (B_*S_)
#define N3 (3*C_)

typedef unsigned short u16;
typedef __bf16 bf16x8 __attribute__((ext_vector_type(8)));
typedef float f32x4 __attribute__((ext_vector_type(4)));

__device__ __forceinline__ u16 f2b(float f){
  union { float f; uint32_t u; } v; v.f = f;
  uint32_t r = (v.u + 0x7FFFu + ((v.u >> 16) & 1u)) >> 16;
  return (u16)r;
}
__device__ __forceinline__ float b2f(u16 h){
  union { uint32_t u; float f; } v; v.u = ((uint32_t)h) << 16;
  return v.f;
}
__device__ __forceinline__ void gload_lds16(const void* g, void* l){
  __builtin_amdgcn_global_load_lds((const __attribute__((address_space(1))) void*)g,
                                   (__attribute__((address_space(3))) void*)l, 16, 0, 0);
}

// ---------------- fused weight convert+transpose: W (K,N) f32 -> Wt (N,K) bf16, 9 mats in 1 launch ----------------
struct WEnt { const float* src; u16* dst; int K; int N; int t0; };
struct WPack { WEnt e[9]; };

__global__ __launch_bounds__(256) void wconv_all_kernel(WPack p){
  __shared__ float tile[32][33];
  const int t = blockIdx.x;
  int i = 0;
  #pragma unroll
  for(int j=1;j<9;j++) if(t >= p.e[j].t0) i = j;
  const float* __restrict__ Wsrc = p.e[i].src;
  u16* __restrict__ Wt = p.e[i].dst;
  const int K = p.e[i].K, N = p.e[i].N;
  const int rel = t - p.e[i].t0;
  const int ntx = N >> 5;
  const int n0 = (rel % ntx) << 5, k0 = (rel / ntx) << 5;
  const int tx = threadIdx.x & 31, ty = threadIdx.x >> 5;
  #pragma unroll
  for(int q=0;q<4;q++)
    tile[ty + q*8][tx] = Wsrc[(size_t)(k0 + ty + q*8) * N + n0 + tx];
  __syncthreads();
  #pragma unroll
  for(int q=0;q<4;q++)
    Wt[(size_t)(n0 + ty + q*8) * K + k0 + tx] = f2b(tile[tx][ty + q*8]);
}

// ---------------- f32 -> bf16 ----------------
__global__ void cvt_kernel(const float* __restrict__ in, u16* __restrict__ out, int n){
  int i = blockIdx.x*256 + threadIdx.x;
  if(i < n) out[i] = f2b(in[i]);
}

// ---------------- LayerNorm over rows of 768, bf16 out ----------------
__global__ __launch_bounds__(256) void ln_kernel(const float* __restrict__ x, const float* __restrict__ g,
    const float* __restrict__ bb, u16* __restrict__ out)
{
  const int row = blockIdx.x;
  const int t = threadIdx.x;
  const float* xr = x + (size_t)row * C_;
  float v0 = xr[t], v1 = xr[t+256], v2 = xr[t+512];
  float s = v0+v1+v2;
  float s2 = v0*v0 + v1*v1 + v2*v2;
  #pragma unroll
  for(int off=32; off>0; off>>=1){ s += __shfl_down(s, off); s2 += __shfl_down(s2, off); }
  __shared__ float red[8];
  const int lane = t & 63, wv = t >> 6;
  if(lane == 0){ red[wv] = s; red[4+wv] = s2; }
  __syncthreads();
  s = red[0]+red[1]+red[2]+red[3];
  s2 = red[4]+red[5]+red[6]+red[7];
  const float mu = s * (1.0f/C_);
  const float inv = rsqrtf(s2*(1.0f/C_) - mu*mu + 1e-5f);
  u16* orow = out + (size_t)row*C_;
  orow[t]     = f2b((v0-mu)*inv*g[t]     + bb[t]);
  orow[t+256] = f2b((v1-mu)*inv*g[t+256] + bb[t+256]);
  orow[t+512] = f2b((v2-mu)*inv*g[t+512] + bb[t+512]);
}

// ---------------- GEMM, 2-phase pipelined (T3 minimum): stage k+1 while computing k, 1 barrier/step ----
__global__ __launch_bounds__(256) void gemm_kernel(
    const u16* __restrict__ A, const u16* __restrict__ Bt,
    u16* __restrict__ Ob, float* __restrict__ Of, const float* __restrict__ resid,
    int Mdim, int Ndim, int Kdim, int outF32)
{
  __shared__ __align__(16) u16 As[2][128*32];
  __shared__ __align__(16) u16 Bs[2][128*32];
  const int tid = threadIdx.x;
  const int lane = tid & 63, w = tid >> 6;
  const int wm = w >> 1, wn = w & 1;
  const int m0 = blockIdx.y * 128, n0 = blockIdx.x * 128;
  f32x4 acc[4][4] = {};
  const int sr = tid >> 2;
  const int sc = (tid & 3) << 3;
  const int l15 = lane & 15, lk = (lane >> 4) << 3;
  // prologue: stage k0=0 into buf 0
  #pragma unroll
  for(int j = 0; j < 2; j++){
    gload_lds16(A  + (size_t)(m0 + sr + (j<<6)) * Kdim + sc, &As[0][(tid<<3) + (j<<11)]);
    gload_lds16(Bt + (size_t)(n0 + sr + (j<<6)) * Kdim + sc, &Bs[0][(tid<<3) + (j<<11)]);
  }
  __syncthreads();
  int cur = 0;
  for(int k0 = 0; k0 < Kdim; k0 += 32){
    if(k0 + 32 < Kdim){   // stage next tile into alternate buffer; flight hides under MFMAs
      #pragma unroll
      for(int j = 0; j < 2; j++){
        gload_lds16(A  + (size_t)(m0 + sr + (j<<6)) * Kdim + k0 + 32 + sc, &As[cur^1][(tid<<3) + (j<<11)]);
        gload_lds16(Bt + (size_t)(n0 + sr + (j<<6)) * Kdim + k0 + 32 + sc, &Bs[cur^1][(tid<<3) + (j<<11)]);
      }
    }
    bf16x8 af[4], bfr[4];
    #pragma unroll
    for(int i=0;i<4;i++) af[i]  = *(const bf16x8*)(&As[cur][(wm*64 + i*16 + l15)*32 + lk]);
    #pragma unroll
    for(int i=0;i<4;i++) bfr[i] = *(const bf16x8*)(&Bs[cur][(wn*64 + i*16 + l15)*32 + lk]);
    #pragma unroll
    for(int mi=0;mi<4;mi++)
      #pragma unroll
      for(int ni=0;ni<4;ni++)
        acc[mi][ni] = __builtin_amdgcn_mfma_f32_16x16x32_bf16(af[mi], bfr[ni], acc[mi][ni], 0,0,0);
    __syncthreads();   // drains staging vmcnt + joins waves; buf swap
    cur ^= 1;
  }
  const int rbase = m0 + wm*64 + ((lane>>4)<<2);
  const int cbase = n0 + wn*64 + l15;
  if(outF32){
    #pragma unroll
    for(int mi=0;mi<4;mi++)
      #pragma unroll
      for(int ni=0;ni<4;ni++)
        #pragma unroll
        for(int r=0;r<4;r++){
          size_t idx = (size_t)(rbase + mi*16 + r) * Ndim + cbase + ni*16;
          Of[idx] = acc[mi][ni][r] + resid[idx];
        }
  } else {
    #pragma unroll
    for(int mi=0;mi<4;mi++)
      #pragma unroll
      for(int ni=0;ni<4;ni++)
        #pragma unroll
        for(int r=0;r<4;r++){
          size_t idx = (size_t)(rbase + mi*16 + r) * Ndim + cbase + ni*16;
          Ob[idx] = f2b(acc[mi][ni][r]);
        }
  }
}

// ---------------- RoPE in-place on q,k slices of qkv (bf16), 16B vectorized ----------------
__global__ void rope_kernel(u16* qkv, const int* hp, const int* wp){
  const int W = wp[0], HH = hp[0];
  int idx = blockIdx.x*256 + threadIdx.x;
  if(idx >= M_*H_*6) return;
  const int c = idx % 6;          // chunk of 8 dims within [0,48)
  int t1 = idx / 6;
  const int h = t1 & 7;
  const int m = t1 >> 3;
  const int d0 = c*8;
  const int s = m & (S_-1);
  const int xc = s % W;
  const int y  = (s / W) % HH;
  const int tf = s / (W*HH);
  float c1v[8], s1v[8], c2v[8], s2v[8];
  #pragma unroll
  for(int j=0;j<8;j++){
    const int d = d0 + j;
    const float invf = __powf(10000.0f, -(float)(d & 15) * (1.0f/16.0f));
    const float pos1 = (float)(d < 32 ? xc : y);
    const float pos2 = (float)(d < 16 ? y : tf);
    __sincosf(pos1 * invf, &s1v[j], &c1v[j]);
    __sincosf(pos2 * invf, &s2v[j], &c2v[j]);
  }
  const size_t base = (size_t)m * N3 + h*DH + d0;
  #pragma unroll
  for(int part=0; part<2; part++){
    u16* p = qkv + base + (size_t)part*C_;
    uint4 lo = *(const uint4*)p;
    uint4 hi = *(const uint4*)(p + 48);
    const u16* lw = (const u16*)&lo; const u16* hw = (const u16*)&hi;
    uint4 olo, ohi; u16* ol = (u16*)&olo; u16* oh = (u16*)&ohi;
    #pragma unroll
    for(int j=0;j<8;j++){
      float x1 = b2f(lw[j]), x2 = b2f(hw[j]);
      ol[j] = f2b(x1*c1v[j] - x2*s1v[j]);
      oh[j] = f2b(x2*c2v[j] + x1*s2v[j]);
    }
    *(uint4*)p = olo;
    *(uint4*)(p + 48) = ohi;
  }
}

// ---------------- V transpose ----------------
__global__ __launch_bounds__(256) void vt_kernel(const u16* __restrict__ src, u16* __restrict__ dst,
                                                 int rowStride, int colOff, int seqLen){
  const int bh = blockIdx.y, b = bh >> 3, h = bh & 7;
  const int s0 = blockIdx.x*64;
  __shared__ u16 t[64][DH+8];
  const int tid = threadIdx.x;
  #pragma unroll
  for(int i=0;i<24;i++){
    int e = tid + i*256; int si = e/DH, d = e - si*DH;
    t[si][d] = src[(size_t)(b*seqLen + s0+si)*rowStride + colOff + h*DH + d];
  }
  __syncthreads();
  #pragma unroll
  for(int i=0;i<24;i++){
    int e = tid + i*256; int d = e >> 6, si = e & 63;
    dst[((size_t)bh*DH + d)*seqLen + s0 + si] = t[si][d];
  }
}

// ---------------- Flash attention, split-KV, 2-phase pipelined K (double-buffer LDS, 2-deep reg
// pipeline), V read direct from L2 (XCD head-grouping keeps it resident), 1 barrier per kv-tile.
// mode 0 = cross (no mask, whole kv, direct write); mode 1 = self causal, kv chunks of 1024.
__global__ __launch_bounds__(256,4) void attn_kernel(
    const u16* __restrict__ qp, int qStride, int qOff,
    const u16* __restrict__ kp, int kStride, int kOff,
    const u16* __restrict__ vt,   // (bh, DH, kvLen)
    u16* __restrict__ op,         // (B*S, C) at col h*DH
    float* __restrict__ part,     // partials: [(bh*16+qt-16)*2+ch] * 6272 floats
    int kvLen, int mode)
{
  __shared__ __align__(16) u16 Ks[2][64][104];
  __shared__ __align__(16) u16 Plds[4][16][72];
  const int lin = blockIdx.x;
  const int xcd = lin & 7;
  const int idx = lin >> 3;
  const int bh = xcd + ((idx & 1) << 3);   // 2 heads per XCD -> K/V L2-resident
  int qt, ch, nCh;
  if(mode == 0){ qt = idx >> 1; ch = 0; nCh = 1; }
  else {
    const int rest = idx >> 1;             // 0..47
    if(rest < 16){ qt = rest; ch = 0; nCh = 1; }
    else { qt = 16 + ((rest - 16) >> 1); ch = (rest - 16) & 1; nCh = 2; }
  }
  const int b = bh >> 3, h = bh & 7;
  const int q0 = qt << 6;
  const int kvA = ch << 10;
  const int kvB = mode ? min(kvA + 1024, q0 + 64) : kvLen;
  const int tA = kvA >> 6, tB = kvB >> 6;
  const int tid = threadIdx.x;
  const int lane = tid & 63, w = tid >> 6;
  const int l15 = lane & 15, lg = lane >> 4, lk = lg << 3;
  const int qrow_base = q0 + w*16;
  const float scale = 0.1020620726159658f;  // 96^-0.5

  bf16x8 qf[3];
  {
    const size_t qb = (size_t)(b*S_ + qrow_base + l15) * qStride + qOff + h*DH;
    #pragma unroll
    for(int ks=0;ks<3;ks++) qf[ks] = *(const bf16x8*)(qp + qb + ks*32 + lk);
  }

  int krow[3], kcol[3];
  #pragma unroll
  for(int r=0;r<3;r++){
    int c = r*256 + tid;
    krow[r] = c/12; kcol[r] = (c - krow[r]*12)*8;
  }
  const u16* kbase = kp + (size_t)b*kvLen*kStride + kOff + h*DH;
  const u16* vbase = vt + (size_t)bh*DH*kvLen;

  uint4 kreg[3];
  // prologue: tile tA -> buf0; tile tA+1 -> regs
  #pragma unroll
  for(int r=0;r<3;r++) kreg[r] = *(const uint4*)(kbase + (size_t)(kvA + krow[r])*kStride + kcol[r]);
  #pragma unroll
  for(int r=0;r<3;r++) *(uint4*)(&Ks[0][krow[r]][kcol[r]]) = kreg[r];
  if(tA+1 < tB){
    #pragma unroll
    for(int r=0;r<3;r++) kreg[r] = *(const uint4*)(kbase + (size_t)(kvA + 64 + krow[r])*kStride + kcol[r]);
  }
  __syncthreads();

  f32x4 oacc[6] = {};
  float mrow[4], lrow[4];
  #pragma unroll
  for(int r=0;r<4;r++){ mrow[r] = -3e38f; lrow[r] = 0.f; }

  int cur = 0;
  for(int t=tA; t<tB; t++){
    const int kv0 = t << 6;
    if(t+1 < tB){   // commit tile t+1 (loaded last iter) into alternate buffer
      #pragma unroll
      for(int r=0;r<3;r++) *(uint4*)(&Ks[cur^1][krow[r]][kcol[r]]) = kreg[r];
    }
    if(t+2 < tB){   // issue loads for tile t+2 (2-deep pipeline; lands during compute)
      #pragma unroll
      for(int r=0;r<3;r++) kreg[r] = *(const uint4*)(kbase + (size_t)(kv0 + 128 + krow[r])*kStride + kcol[r]);
    }
    // === QK^T from Ks[cur] ===
    f32x4 sacc[4] = {};
    #pragma unroll
    for(int nt=0;nt<4;nt++){
      #pragma unroll
      for(int ks=0;ks<3;ks++){
        bf16x8 kf = *(const bf16x8*)(&Ks[cur][nt*16+l15][ks*32+lk]);
        sacc[nt] = __builtin_amdgcn_mfma_f32_16x16x32_bf16(qf[ks], kf, sacc[nt], 0,0,0);
      }
    }
    // === mask + online softmax ===
    const bool doMask = (mode != 0) && (kv0 + 64 > qrow_base);
    float mt[4];
    #pragma unroll
    for(int r=0;r<4;r++) mt[r] = -3e38f;
    #pragma unroll
    for(int nt=0;nt<4;nt++)
      #pragma unroll
      for(int r=0;r<4;r++){
        float v = sacc[nt][r] * scale;
        if(doMask && (kv0 + nt*16 + l15 > qrow_base + (lg<<2) + r)) v = -3e38f;
        sacc[nt][r] = v;
        mt[r] = fmaxf(mt[r], v);
      }
    #pragma unroll
    for(int r=0;r<4;r++){
      #pragma unroll
      for(int off=1; off<16; off<<=1) mt[r] = fmaxf(mt[r], __shfl_xor(mt[r], off));
    }
    float al[4], rs[4];
    #pragma unroll
    for(int r=0;r<4;r++){
      float mn = fmaxf(mrow[r], mt[r]);
      al[r] = __expf(mrow[r] - mn);
      mrow[r] = mn;
      rs[r] = 0.f;
    }
    #pragma unroll
    for(int nt=0;nt<4;nt++)
      #pragma unroll
      for(int r=0;r<4;r++){
        float pv = __expf(sacc[nt][r] - mrow[r]);
        sacc[nt][r] = pv;
        rs[r] += pv;
      }
    #pragma unroll
    for(int r=0;r<4;r++){
      #pragma unroll
      for(int off=1; off<16; off<<=1) rs[r] += __shfl_xor(rs[r], off);
      lrow[r] = lrow[r]*al[r] + rs[r];
    }
    #pragma unroll
    for(int n=0;n<6;n++)
      #pragma unroll
      for(int r=0;r<4;r++) oacc[n][r] *= al[r];
    // P -> per-wave private LDS (padded stride 72, ~2-way max)
    #pragma unroll
    for(int nt=0;nt<4;nt++)
      #pragma unroll
      for(int r=0;r<4;r++)
        Plds[w][(lg<<2)+r][nt*16+l15] = f2b(sacc[nt][r]);
    // === PV: V fragments direct from global (L2-resident), P from private LDS ===
    #pragma unroll
    for(int kk=0;kk<2;kk++){
      bf16x8 pf = *(const bf16x8*)(&Plds[w][l15][kk*32 + lk]);
      #pragma unroll
      for(int n=0;n<6;n++){
        bf16x8 vf = *(const bf16x8*)(vbase + (size_t)(n*16+l15)*kvLen + kv0 + kk*32 + lk);
        oacc[n] = __builtin_amdgcn_mfma_f32_16x16x32_bf16(pf, vf, oacc[n], 0,0,0);
      }
    }
    __syncthreads();   // joins waves; Ks[cur^1] fully written for next iter
    cur ^= 1;
  }
  if(nCh == 1){
    #pragma unroll
    for(int n=0;n<6;n++)
      #pragma unroll
      for(int r=0;r<4;r++){
        const int qq = qrow_base + (lg<<2) + r;
        op[(size_t)(b*S_ + qq)*C_ + h*DH + n*16 + l15] = f2b(oacc[n][r] / lrow[r]);
      }
  } else {
    float* pb = part + (size_t)((((bh<<4) + (qt-16))<<1) + ch) * 6272;
    #pragma unroll
    for(int n=0;n<6;n++)
      #pragma unroll
      for(int r=0;r<4;r++)
        pb[(w*16 + (lg<<2) + r)*96 + n*16 + l15] = oacc[n][r];
    if(l15 == 0){
      #pragma unroll
      for(int r=0;r<4;r++){
        pb[6144 + w*16 + (lg<<2) + r] = mrow[r];
        pb[6208 + w*16 + (lg<<2) + r] = lrow[r];
      }
    }
  }
}

// ---------------- combine 2 kv-chunk partials -> normalized bf16 output (qt>=16 only) ----------------
__global__ void attn_combine_kernel(const float* __restrict__ part, u16* __restrict__ op){
  const int i = blockIdx.x*256 + threadIdx.x;
  if(i >= 16*16*64*96) return;
  const int col = i % 96;
  const int r2 = i / 96;
  const int row = r2 & 63;
  const int r3 = r2 >> 6;
  const int qt16 = r3 & 15, bh = r3 >> 4;
  const float* p0 = part + (size_t)(((bh<<4)+qt16)<<1) * 6272;
  const float* p1 = p0 + 6272;
  const float m0 = p0[6144+row], l0 = p0[6208+row];
  const float m1 = p1[6144+row], l1 = p1[6208+row];
  const float Mx = fmaxf(m0, m1);
  const float w0 = __expf(m0-Mx), w1 = __expf(m1-Mx);
  const float o = (p0[row*96+col]*w0 + p1[row*96+col]*w1) / (l0*w0 + l1*w1);
  const int bq = bh >> 3, hq = bh & 7;
  const int q = ((qt16+16)<<6) + row;
  op[(size_t)(bq*S_ + q)*C_ + hq*DH + col] = f2b(o);
}

// ---------------- SiLU(gate) * up from fused (M, 2I) buffer -> (M, I) bf16, 8-wide ----------------
__global__ void silu_kernel(const u16* __restrict__ gu, u16* __restrict__ obuf, int n8){
  int i = blockIdx.x*256 + threadIdx.x;
  if(i >= n8) return;
  int m = i / (I_/8), c = i - m*(I_/8);
  const uint4 g = *(const uint4*)(gu + (size_t)m*(2*I_) + c*8);
  const uint4 u = *(const uint4*)(gu + (size_t)m*(2*I_) + I_ + c*8);
  const u16* gp = (const u16*)&g; const u16* up = (const u16*)&u;
  uint4 o;
  u16* opw = (u16*)&o;
  #pragma unroll
  for(int j=0;j<8;j++){
    float xg = b2f(gp[j]), yu = b2f(up[j]);
    opw[j] = f2b(xg / (1.0f + __expf(-xg)) * yu);
  }
  *(uint4*)(obuf + (size_t)i*8) = o;
}

extern "C" void kernel_launch(void* const* d_in, const int* in_sizes, int n_in,
                              void* d_out, int out_size, void* d_ws, size_t ws_size,
                              hipStream_t stream)
{
  (void)in_sizes; (void)n_in; (void)out_size;
  const float* x    = (const float*)d_in[0];
  const float* ctxF = (const float*)d_in[1];
  const float* wqkvF= (const float*)d_in[2];
  const float* waoF = (const float*)d_in[3];
  const float* ln1g = (const float*)d_in[4];
  const float* ln1b = (const float*)d_in[5];
  const float* wqcF = (const float*)d_in[6];
  const float* wkcF = (const float*)d_in[7];
  const float* wvcF = (const float*)d_in[8];
  const float* wcoF = (const float*)d_in[9];
  const float* ln2g = (const float*)d_in[10];
  const float* ln2b = (const float*)d_in[11];
  const float* wgF  = (const float*)d_in[12];
  const float* wuF  = (const float*)d_in[13];
  const float* wdF  = (const float*)d_in[14];
  const float* ln3g = (const float*)d_in[15];
  const float* ln3b = (const float*)d_in[16];
  const int* hgt = (const int*)d_in[17];
  const int* wid = (const int*)d_in[18];
  float* out = (float*)d_out;

  char* base = (char*)d_ws;
  size_t off = 0;
  auto alloc = [&](size_t bytes)->void*{
    void* r = base + off;
    off += (bytes + 255) & ~(size_t)255;
    return r;
  };
  u16* wqkvT = (u16*)alloc((size_t)N3*C_*2);
  u16* waoT  = (u16*)alloc((size_t)C_*C_*2);
  u16* wqcT  = (u16*)alloc((size_t)C_*C_*2);
  u16* wkvcT = (u16*)alloc((size_t)2*C_*C_*2);
  u16* wcoT  = (u16*)alloc((size_t)C_*C_*2);
  u16* wguT  = (u16*)alloc((size_t)2*I_*C_*2);
  u16* wdT   = (u16*)alloc((size_t)C_*I_*2);
  u16* ctxb  = (u16*)alloc((size_t)B_*CTX*C_*2);
  u16* xn    = (u16*)alloc((size_t)M_*C_*2);
  u16* gateb = (u16*)alloc((size_t)M_*I_*2);    // also holds attn partials (12.85 MB) pre-MLP
  float* x1  = (float*)alloc((size_t)M_*C_*4);
  float* x2  = (float*)alloc((size_t)M_*C_*4);
  char* uni  = (char*)alloc((size_t)M_*2*I_*2);  // 50.33 MB transient union
  u16* qkvb = (u16*)uni;                                      // 18.87 MB
  u16* vtb  = (u16*)(uni + 18874368);                         //  6.29 MB
  u16* obuf = (u16*)(uni + 18874368 + 1*6291456);             //  6.29 MB
  u16* qcb  = (u16*)(uni + 18874368 + 2*6291456);             //  6.29 MB
  u16* kvcb = (u16*)(uni + 18874368 + 3*6291456);             //  0.79 MB
  u16* vctb = (u16*)(uni + 18874368 + 3*6291456 + 786432);    //  0.39 MB
  u16* gub  = (u16*)uni;                                      // MLP phase only
  float* part = (float*)gateb;                                // attn phase only
  if(off > ws_size) return;

  dim3 blk(256);
  // fused weight conversion: 9 matrices, 1 launch
  WPack wp;
  wp.e[0] = { wqkvF, wqkvT,               C_, N3,   0 };
  wp.e[1] = { waoF,  waoT,                C_, C_,   1728 };
  wp.e[2] = { wqcF,  wqcT,                C_, C_,   2304 };
  wp.e[3] = { wkcF,  wkvcT,               C_, C_,   2880 };
  wp.e[4] = { wvcF,  wkvcT + (size_t)C_*C_, C_, C_, 3456 };
  wp.e[5] = { wcoF,  wcoT,                C_, C_,   4032 };
  wp.e[6] = { wgF,   wguT,                C_, I_,   4608 };
  wp.e[7] = { wuF,   wguT + (size_t)I_*C_,  C_, I_, 6912 };
  wp.e[8] = { wdF,   wdT,                 I_, C_,   9216 };
  wconv_all_kernel<<<dim3(11520), blk, 0, stream>>>(wp);
  cvt_kernel<<<dim3((B_*CTX*C_+255)/256), blk, 0, stream>>>(ctxF, ctxb, B_*CTX*C_);

  // ---- self attention ----
  ln_kernel<<<dim3(M_), blk, 0, stream>>>(x, ln1g, ln1b, xn);
  gemm_kernel<<<dim3(N3/128, M_/128), blk, 0, stream>>>(xn, wqkvT, qkvb, nullptr, nullptr, M_, N3, C_, 0);
  rope_kernel<<<dim3((M_*H_*6+255)/256), blk, 0, stream>>>(qkvb, hgt, wid);
  vt_kernel<<<dim3(S_/64, B_*H_), blk, 0, stream>>>(qkvb, vtb, N3, 2*C_, S_);
  attn_kernel<<<dim3(768), blk, 0, stream>>>(qkvb, N3, 0, qkvb, N3, C_, vtb, obuf, part, S_, 1);
  attn_combine_kernel<<<dim3(16*16*64*96/256), blk, 0, stream>>>(part, obuf);
  gemm_kernel<<<dim3(C_/128, M_/128), blk, 0, stream>>>(obuf, waoT, nullptr, x1, x, M_, C_, C_, 1);

  // ---- cross attention ----
  ln_kernel<<<dim3(M_), blk, 0, stream>>>(x1, ln2g, ln2b, xn);
  gemm_kernel<<<dim3(C_/128, M_/128), blk, 0, stream>>>(xn, wqcT, qcb, nullptr, nullptr, M_, C_, C_, 0);
  gemm_kernel<<<dim3(2*C_/128, (B_*CTX)/128), blk, 0, stream>>>(ctxb, wkvcT, kvcb, nullptr, nullptr, B_*CTX, 2*C_, C_, 0);
  vt_kernel<<<dim3(CTX/64, B_*H_), blk, 0, stream>>>(kvcb, vctb, 2*C_, C_, CTX);
  attn_kernel<<<dim3(512), blk, 0, stream>>>(qcb, C_, 0, kvcb, 2*C_, 0, vctb, obuf, nullptr, CTX, 0);
  gemm_kernel<<<dim3(C_/128, M_/128), blk, 0, stream>>>(obuf, wcoT, nullptr, x2, x1, M_, C_, C_, 1);

  // ---- MLP ----
  ln_kernel<<<dim3(M_), blk, 0, stream>>>(x2, ln3g, ln3b, xn);
  gemm_kernel<<<dim3(2*I_/128, M_/128), blk, 0, stream>>>(xn, wguT, gub, nullptr, nullptr, M_, 2*I_, C_, 0);
  silu_kernel<<<dim3(M_*I_/8/256), blk, 0, stream>>>(gub, gateb, M_*I_/8);
  gemm_kernel<<<dim3(C_/128, M_/128), blk, 0, stream>>>(gateb, wdT, nullptr, out, x2, M_, C_, I_, 1);
}